// Round 8
// baseline (128.150 us; speedup 1.0000x reference)
//
#include <hip/hip_runtime.h>
#include <math.h>

#define T_LEN  220500
#define SEG    64                          // samples per lane
#define TPB    64                          // one wave per block
#define WARML  8                           // warm lanes (512-sample zero-state warmup)
#define WOUT   ((64 - WARML) * SEG)        // 3584 output samples per wave/window
#define PRE    (WARML * SEG + 4)           // 516 floats staged before window output
#define RSAMP  (WOUT + PRE)                // 4100 staged floats per window
#define RS4    (RSAMP / 4)                 // 1025 float4 slots
#define NWIN   ((T_LEN + WOUT - 1) / WOUT) // 62 windows per sequence

// XOR swizzle on float4-slot index (involution, flips bits 0..2 only).
// Conflict-free for: coalesced stage-write (lane->slot consecutive),
// per-lane segment read (lane l -> slots ~l*16+i), pass-B in-place write
// (same pattern), and coalesced flush read (lane -> slot 64k+lane).
__device__ __forceinline__ int swz(int s) { return s ^ ((s >> 4) & 7); }

// One wave per 3584-sample output window.
//  stage : 17 coalesced float4 loads -> swizzled LDS (zero-fill at edges)
//  read  : each lane ds_read_b128s its 64-sample segment into registers
//  pass A: zero-state scan of own segment (exact FIR history from LDS)
//  scan  : 4-step __shfl_up affine scan, matrices A^(64*2^k); 1024-sample
//          window is numerically exact (|A^1024| ~ 1e-9, poles r <= 0.9801)
//  pass B: re-scan from exact state, write output in place to swizzled LDS
//  flush : coalesced float4 stores
// First 8 lanes are warm-up (512-sample zero-state transient ~2e-4 << thr).
__global__ __launch_bounds__(TPB) void bandpass_kernel(
    const float* __restrict__ x,
    const int* __restrict__ sr_p,
    const float* __restrict__ fl_p,
    const float* __restrict__ fh_p,
    float* __restrict__ out)
{
    __shared__ float4 lds4[RS4];

    const int lane = threadIdx.x;          // 0..63
    const int win  = blockIdx.x;           // 0..NWIN-1
    const int seq  = blockIdx.y;

    // ---- fp32 biquad coefficients (reference computes in fp32 too) ----
    const float sr   = (float)sr_p[0];
    const float twoQ = (float)(2.0 * 0.707);

    float w0 = (float)(2.0 * M_PI) * fl_p[0] / sr;
    float cw = cosf(w0);
    float al = sinf(w0) / twoQ;
    float a0 = 1.0f + al;
    const float lb0  = (1.0f - cw) * 0.5f / a0;
    const float lb1  = (1.0f - cw) / a0;
    const float lb2  = lb0;
    const float lna1 = 2.0f * cw / a0;        // = -a1/a0
    const float lna2 = -(1.0f - al) / a0;     // = -a2/a0

    w0 = (float)(2.0 * M_PI) * fh_p[0] / sr;
    cw = cosf(w0);
    al = sinf(w0) / twoQ;
    a0 = 1.0f + al;
    const float hb0  = (1.0f + cw) * 0.5f / a0;
    const float hb1  = -(1.0f + cw) / a0;
    const float hb2  = hb0;
    const float hna1 = 2.0f * cw / a0;
    const float hna2 = -(1.0f - al) / a0;

    const float* __restrict__ xs = x   + (size_t)seq * T_LEN;
    float*       __restrict__ os = out + (size_t)seq * T_LEN;

    const int Wbase = win * WOUT;
    const int G0    = Wbase - PRE;             // region float 0 (multiple of 4)

    // ---- stage: coalesced float4 loads -> swizzled LDS (OOB -> 0) ----
    for (int s4 = lane; s4 < RS4; s4 += TPB) { // 17 iterations
        const int g = G0 + 4 * s4;
        float4 v;
        if (g >= 0 && g + 4 <= T_LEN) {
            v = *(const float4*)(xs + g);
        } else {
            float e[4];
#pragma unroll
            for (int k = 0; k < 4; ++k) {
                const int gg = g + k;
                e[k] = (gg >= 0 && gg < T_LEN) ? xs[gg] : 0.f;
            }
            v = make_float4(e[0], e[1], e[2], e[3]);
        }
        lds4[swz(s4)] = v;
    }
    __syncthreads();

    // ---- per-lane segment read: 16 x ds_read_b128, swizzle-spread banks ----
    const int b = 1 + lane * 16;               // segment base slot (region f 4+lane*64)
    float4 xr[16];
#pragma unroll
    for (int i = 0; i < 16; ++i) xr[i] = lds4[swz(b + i)];

    // exact x-history from LDS: region floats (3 + lane*64), (2 + lane*64)
    const float* ldsf = (const float*)lds4;
    const int jh = 3 + lane * 64;              // slot = lane*16, words 3 and 2
    const float xh1 = ldsf[4 * swz(jh >> 2) + 3];
    const float xh2 = ldsf[4 * swz(jh >> 2) + 2];

    // ---- pass A: zero-state scan of own segment ----
    float x1 = xh1, x2 = xh2;
    float ly1 = 0.f, ly2 = 0.f, hy1 = 0.f, hy2 = 0.f;
#pragma unroll
    for (int i = 0; i < 16; ++i) {
        const float xa[4] = {xr[i].x, xr[i].y, xr[i].z, xr[i].w};
#pragma unroll
        for (int k = 0; k < 4; ++k) {
            const float xc  = xa[k];
            const float ffl = fmaf(lb0, xc, fmaf(lb1, x1, lb2 * x2));
            const float yl  = fmaf(lna2, ly2, fmaf(lna1, ly1, ffl));
            const float ffh = fmaf(hb0, xc, fmaf(hb1, x1, hb2 * x2));
            const float yh  = fmaf(hna2, hy2, fmaf(hna1, hy1, ffh));
            ly2 = ly1; ly1 = yl; hy2 = hy1; hy1 = yh;
            x2 = x1; x1 = xc;
        }
    }

    // ---- A^64 via 6 fp32 squarings (A = [[na1,na2],[1,0]]) ----
    float la = lna1, lb = lna2, lc = 1.0f, ld = 0.0f;
    float ha = hna1, hb = hna2, hc = 1.0f, hd = 0.0f;
#pragma unroll
    for (int i = 0; i < 6; ++i) {
        float t0 = fmaf(la, la, lb * lc), t1 = fmaf(la, lb, lb * ld);
        float t2 = fmaf(lc, la, ld * lc), t3 = fmaf(lc, lb, ld * ld);
        la = t0; lb = t1; lc = t2; ld = t3;
        t0 = fmaf(ha, ha, hb * hc); t1 = fmaf(ha, hb, hb * hd);
        t2 = fmaf(hc, ha, hd * hc); t3 = fmaf(hc, hb, hd * hd);
        ha = t0; hb = t1; hc = t2; hd = t3;
    }

    // ---- 4-step shfl_up affine scan (distances 1,2,4,8 segments) ----
    float4 p = make_float4(ly1, ly2, hy1, hy2);
#pragma unroll
    for (int k = 0; k < 4; ++k) {
        const int d = 1 << k;
        float qx = __shfl_up(p.x, d, 64);
        float qy = __shfl_up(p.y, d, 64);
        float qz = __shfl_up(p.z, d, 64);
        float qw = __shfl_up(p.w, d, 64);
        if (lane < d) { qx = 0.f; qy = 0.f; qz = 0.f; qw = 0.f; }
        p.x = fmaf(la, qx, fmaf(lb, qy, p.x));
        p.y = fmaf(lc, qx, fmaf(ld, qy, p.y));
        p.z = fmaf(ha, qz, fmaf(hb, qw, p.z));
        p.w = fmaf(hc, qz, fmaf(hd, qw, p.w));
        // M <- M*M  (A^(64*2^(k+1)))
        float t0 = fmaf(la, la, lb * lc), t1 = fmaf(la, lb, lb * ld);
        float t2 = fmaf(lc, la, ld * lc), t3 = fmaf(lc, lb, ld * ld);
        la = t0; lb = t1; lc = t2; ld = t3;
        t0 = fmaf(ha, ha, hb * hc); t1 = fmaf(ha, hb, hb * hd);
        t2 = fmaf(hc, ha, hd * hc); t3 = fmaf(hc, hb, hd * hd);
        ha = t0; hb = t1; hc = t2; hd = t3;
    }
    // exclusive prefix = inclusive of lane-1
    float sx0 = __shfl_up(p.x, 1, 64);
    float sx1 = __shfl_up(p.y, 1, 64);
    float sx2 = __shfl_up(p.z, 1, 64);
    float sx3 = __shfl_up(p.w, 1, 64);
    if (lane == 0) { sx0 = 0.f; sx1 = 0.f; sx2 = 0.f; sx3 = 0.f; }

    __syncthreads();   // all LDS input reads done before in-place overwrite

    // ---- pass B: re-scan from exact state, write output in place ----
    if (lane >= WARML) {
        float bx1 = xh1, bx2 = xh2;
        float Ly1 = sx0, Ly2 = sx1, Hy1 = sx2, Hy2 = sx3;
#pragma unroll
        for (int i = 0; i < 16; ++i) {
            const float xa[4] = {xr[i].x, xr[i].y, xr[i].z, xr[i].w};
            float o[4];
#pragma unroll
            for (int k = 0; k < 4; ++k) {
                const float xc  = xa[k];
                const float ffl = fmaf(lb0, xc, fmaf(lb1, bx1, lb2 * bx2));
                const float yl  = fmaf(lna2, Ly2, fmaf(lna1, Ly1, ffl));
                const float ffh = fmaf(hb0, xc, fmaf(hb1, bx1, hb2 * bx2));
                const float yh  = fmaf(hna2, Hy2, fmaf(hna1, Hy1, ffh));
                Ly2 = Ly1; Ly1 = yl; Hy2 = Hy1; Hy1 = yh;
                bx2 = bx1; bx1 = xc;
                o[k] = yl - yh;
            }
            lds4[swz(b + i)] = make_float4(o[0], o[1], o[2], o[3]);
        }
    }
    __syncthreads();   // LDS writes visible before cross-lane flush reads

    // ---- flush: coalesced float4 stores (output slots 129..1024) ----
#pragma unroll
    for (int k = 0; k < WOUT / 4 / TPB; ++k) {   // 14
        const int slot = (PRE / 4) + 64 * k + lane;
        const int g = G0 + 4 * slot;             // = Wbase + 4*(64k+lane)
        if (g < T_LEN) *(float4*)(os + g) = lds4[swz(slot)];
    }
}

extern "C" void kernel_launch(void* const* d_in, const int* in_sizes, int n_in,
                              void* d_out, int out_size, void* d_ws, size_t ws_size,
                              hipStream_t stream) {
    const float* x  = (const float*)d_in[0];
    const int*   sr = (const int*)d_in[1];
    const float* fl = (const float*)d_in[2];
    const float* fh = (const float*)d_in[3];
    float* outp = (float*)d_out;

    const int nseq = in_sizes[0] / T_LEN;      // 64

    dim3 block(TPB);
    dim3 grid(NWIN, nseq);                     // 62 x 64 = 3968 waves
    hipLaunchKernelGGL(bandpass_kernel, grid, block, 0, stream,
                       x, sr, fl, fh, outp);
}

// Round 9
// 116.040 us; speedup vs baseline: 1.1044x; 1.1044x over previous
//
#include <hip/hip_runtime.h>
#include <math.h>
#include <stdint.h>

#define T_LEN  220500
#define SEG    32                           // samples per lane
#define TPB    128                          // 2 waves per block, independent windows
#define WARML  16                           // warm lanes (16*32 = 512-sample warmup)
#define WOUT   ((64 - WARML) * SEG)         // 1536 output samples per window
#define RS4    512                          // staged float4 slots per window (2048 floats)
#define NWIN   ((T_LEN + WOUT - 1) / WOUT)  // 144 windows per sequence (even)
#define NBX    (NWIN / 2)                   // 72 blocks in x

// Bank swizzle on float4-slot index (involution; flips bits 0..2 by bits 3..5,
// stays within each 64-slot group). Segment read: lane l, slot 8l+i ->
// swz = 8l + (i^(l&7)); bank-quad = i^(l&7): any 8 consecutive lanes hit 8
// distinct quads -> conflict-optimal 8-phase ds_read_b128. Flush read
// (slot 64k+lane) is a within-group permutation of consecutive slots -> optimal.
__device__ __forceinline__ int swz(int s) { return s ^ ((s >> 3) & 7); }

// async global->LDS, 16B per lane: LDS dest = uniform base + lane*16 (linear);
// swizzle achieved by pre-swizzling the per-lane GLOBAL source index.
__device__ __forceinline__ void glds16(const float* src, float4* dst_lds) {
    __builtin_amdgcn_global_load_lds(
        (const __attribute__((address_space(1))) void*)src,
        (__attribute__((address_space(3))) void*)dst_lds,
        16, 0, 0);
}

// One wave per 2048-sample window (512 warm + 1536 output).
//  stage : 8x global_load_lds (coalesced 64-f4 groups, source pre-swizzled)
//  read  : per-lane segment (8x ds_read_b128, conflict-optimal via swz)
//  pass A: zero-state scan of own 32-sample segment (exact FIR history)
//  scan  : 5-step __shfl_up affine scan, matrices A^(32*2^k); effective
//          1024-sample window; |A^1024| ~ 1e-9 (poles r <= 0.9801) -> exact
//  pass B: re-scan from exact state, write output in place to swizzled LDS
//  flush : coalesced float4 stores
// Warm lanes: 512-sample zero-state transient ~2e-4 << 9.4e-3 threshold.
__global__ __launch_bounds__(TPB) void bandpass_kernel(
    const float* __restrict__ x,
    const int* __restrict__ sr_p,
    const float* __restrict__ fl_p,
    const float* __restrict__ fh_p,
    float* __restrict__ out,
    const float* __restrict__ zbuf)
{
    __shared__ float4 lds4[2][RS4];        // 16 KB/block

    const int tid  = threadIdx.x;
    const int lane = tid & 63;
    const int wv   = tid >> 6;
    const int win  = blockIdx.x * 2 + wv;  // 0..143
    const int seq  = blockIdx.y;

    // ---- fp32 biquad coefficients (reference computes in fp32 too) ----
    const float sr   = (float)sr_p[0];
    const float twoQ = (float)(2.0 * 0.707);

    float w0 = (float)(2.0 * M_PI) * fl_p[0] / sr;
    float cw = cosf(w0);
    float al = sinf(w0) / twoQ;
    float a0 = 1.0f + al;
    const float lb0  = (1.0f - cw) * 0.5f / a0;
    const float lb1  = (1.0f - cw) / a0;
    const float lb2  = lb0;
    const float lna1 = 2.0f * cw / a0;        // = -a1/a0
    const float lna2 = -(1.0f - al) / a0;     // = -a2/a0

    w0 = (float)(2.0 * M_PI) * fh_p[0] / sr;
    cw = cosf(w0);
    al = sinf(w0) / twoQ;
    a0 = 1.0f + al;
    const float hb0  = (1.0f + cw) * 0.5f / a0;
    const float hb1  = -(1.0f + cw) / a0;
    const float hb2  = hb0;
    const float hna1 = 2.0f * cw / a0;
    const float hna2 = -(1.0f - al) / a0;

    const float* __restrict__ xs = x   + (size_t)seq * T_LEN;
    float*       __restrict__ os = out + (size_t)seq * T_LEN;

    const int Wbase = win * WOUT;              // first output sample
    const int G0    = Wbase - WARML * SEG;     // region float 0 (mult of 4)

    float4* ldsw = lds4[wv];

    // ---- stage: 8 async DMA loads, pre-swizzled source, OOB -> zero page ----
#pragma unroll
    for (int k = 0; k < 8; ++k) {
        const int jsrc = 64 * k + (lane ^ ((lane >> 3) & 7));  // = swz(64k+lane)
        const int g    = G0 + 4 * jsrc;
        const float* src = (g >= 0 && g + 4 <= T_LEN) ? (xs + g) : zbuf;
        glds16(src, &ldsw[64 * k]);
    }
    __syncthreads();   // drains vmcnt(0) before barrier -> LDS valid

    // ---- exact FIR x-history: floats 32*lane-1, -2 (lane-1's last slot) ----
    float xh1, xh2;
    if (lane > 0) {
        const float4 h = ldsw[swz(8 * lane - 1)];
        xh1 = h.w; xh2 = h.z;
    } else {
        xh1 = (G0 >= 1) ? xs[G0 - 1] : 0.f;
        xh2 = (G0 >= 2) ? xs[G0 - 2] : 0.f;
    }

    // ---- per-lane segment: 8x ds_read_b128 into registers ----
    const int b = 8 * lane;
    float4 xr[8];
#pragma unroll
    for (int i = 0; i < 8; ++i) xr[i] = ldsw[swz(b + i)];

    // ---- pass A: zero-state scan of own segment ----
    float x1 = xh1, x2 = xh2;
    float ly1 = 0.f, ly2 = 0.f, hy1 = 0.f, hy2 = 0.f;
#pragma unroll
    for (int i = 0; i < 8; ++i) {
        const float xa[4] = {xr[i].x, xr[i].y, xr[i].z, xr[i].w};
#pragma unroll
        for (int k = 0; k < 4; ++k) {
            const float xc  = xa[k];
            const float ffl = fmaf(lb0, xc, fmaf(lb1, x1, lb2 * x2));
            const float yl  = fmaf(lna2, ly2, fmaf(lna1, ly1, ffl));
            const float ffh = fmaf(hb0, xc, fmaf(hb1, x1, hb2 * x2));
            const float yh  = fmaf(hna2, hy2, fmaf(hna1, hy1, ffh));
            ly2 = ly1; ly1 = yl; hy2 = hy1; hy1 = yh;
            x2 = x1; x1 = xc;
        }
    }

    // ---- A^32 via 5 fp32 squarings (A = [[na1,na2],[1,0]]) ----
    float la = lna1, lb = lna2, lc = 1.0f, ld = 0.0f;
    float ha = hna1, hb = hna2, hc = 1.0f, hd = 0.0f;
#pragma unroll
    for (int i = 0; i < 5; ++i) {
        float t0 = fmaf(la, la, lb * lc), t1 = fmaf(la, lb, lb * ld);
        float t2 = fmaf(lc, la, ld * lc), t3 = fmaf(lc, lb, ld * ld);
        la = t0; lb = t1; lc = t2; ld = t3;
        t0 = fmaf(ha, ha, hb * hc); t1 = fmaf(ha, hb, hb * hd);
        t2 = fmaf(hc, ha, hd * hc); t3 = fmaf(hc, hb, hd * hd);
        ha = t0; hb = t1; hc = t2; hd = t3;
    }

    // ---- 5-step shfl_up affine scan (distances 1,2,4,8,16 segments) ----
    float4 p = make_float4(ly1, ly2, hy1, hy2);
#pragma unroll
    for (int k = 0; k < 5; ++k) {
        const int d = 1 << k;
        float qx = __shfl_up(p.x, d, 64);
        float qy = __shfl_up(p.y, d, 64);
        float qz = __shfl_up(p.z, d, 64);
        float qw = __shfl_up(p.w, d, 64);
        if (lane < d) { qx = 0.f; qy = 0.f; qz = 0.f; qw = 0.f; }
        p.x = fmaf(la, qx, fmaf(lb, qy, p.x));
        p.y = fmaf(lc, qx, fmaf(ld, qy, p.y));
        p.z = fmaf(ha, qz, fmaf(hb, qw, p.z));
        p.w = fmaf(hc, qz, fmaf(hd, qw, p.w));
        // M <- M*M  (A^(32*2^(k+1)))
        float t0 = fmaf(la, la, lb * lc), t1 = fmaf(la, lb, lb * ld);
        float t2 = fmaf(lc, la, ld * lc), t3 = fmaf(lc, lb, ld * ld);
        la = t0; lb = t1; lc = t2; ld = t3;
        t0 = fmaf(ha, ha, hb * hc); t1 = fmaf(ha, hb, hb * hd);
        t2 = fmaf(hc, ha, hd * hc); t3 = fmaf(hc, hb, hd * hd);
        ha = t0; hb = t1; hc = t2; hd = t3;
    }
    // exclusive prefix = inclusive of lane-1
    float sx0 = __shfl_up(p.x, 1, 64);
    float sx1 = __shfl_up(p.y, 1, 64);
    float sx2 = __shfl_up(p.z, 1, 64);
    float sx3 = __shfl_up(p.w, 1, 64);
    if (lane == 0) { sx0 = 0.f; sx1 = 0.f; sx2 = 0.f; sx3 = 0.f; }

    // ---- pass B: re-scan from exact state, write output in place ----
    if (lane >= WARML) {
        float bx1 = xh1, bx2 = xh2;
        float Ly1 = sx0, Ly2 = sx1, Hy1 = sx2, Hy2 = sx3;
#pragma unroll
        for (int i = 0; i < 8; ++i) {
            const float xa[4] = {xr[i].x, xr[i].y, xr[i].z, xr[i].w};
            float o[4];
#pragma unroll
            for (int k = 0; k < 4; ++k) {
                const float xc  = xa[k];
                const float ffl = fmaf(lb0, xc, fmaf(lb1, bx1, lb2 * bx2));
                const float yl  = fmaf(lna2, Ly2, fmaf(lna1, Ly1, ffl));
                const float ffh = fmaf(hb0, xc, fmaf(hb1, bx1, hb2 * bx2));
                const float yh  = fmaf(hna2, Hy2, fmaf(hna1, Hy1, ffh));
                Ly2 = Ly1; Ly1 = yl; Hy2 = Hy1; Hy1 = yh;
                bx2 = bx1; bx1 = xc;
                o[k] = yl - yh;
            }
            ldsw[swz(b + i)] = make_float4(o[0], o[1], o[2], o[3]);
        }
    }
    __syncthreads();   // LDS writes visible before cross-lane flush reads

    // ---- flush: coalesced float4 stores (output slots 128..511) ----
#pragma unroll
    for (int k = 0; k < 6; ++k) {
        const int slot = 128 + 64 * k + lane;
        const int g = Wbase + 4 * (64 * k + lane);
        if (g < T_LEN) *(float4*)(os + g) = ldsw[swz(slot)];
    }
}

extern "C" void kernel_launch(void* const* d_in, const int* in_sizes, int n_in,
                              void* d_out, int out_size, void* d_ws, size_t ws_size,
                              hipStream_t stream) {
    const float* x  = (const float*)d_in[0];
    const int*   sr = (const int*)d_in[1];
    const float* fl = (const float*)d_in[2];
    const float* fh = (const float*)d_in[3];
    float* outp = (float*)d_out;

    // zero page for OOB staging lanes (d_ws is re-poisoned before every call)
    hipMemsetAsync(d_ws, 0, 256, stream);

    const int nseq = in_sizes[0] / T_LEN;      // 64

    dim3 block(TPB);
    dim3 grid(NBX, nseq);                      // 72 x 64 blocks = 9216 waves
    hipLaunchKernelGGL(bandpass_kernel, grid, block, 0, stream,
                       x, sr, fl, fh, outp, (const float*)d_ws);
}